// Round 1
// 618.847 us; speedup vs baseline: 1.0887x; 1.0887x over previous
//
#include <hip/hip_runtime.h>
#include <math.h>

#define N_TOK 65536
#define D_DIM 256
#define C_NUM 1024

// d_out layout (floats): out (D*N) | indices (N) | loss (1) | distances (N*C)
#define OUT_OFF   0
#define IDX_OFF   (D_DIM * N_TOK)            // 16777216
#define LOSS_OFF  (IDX_OFF + N_TOK)          // 16842752
#define DIST_OFF  (LOSS_OFF + 1)             // 16842753

// scratch inside the out region (dead until k4 overwrites it):
//   EhG: 262144 u16 (= 131072 floats) at float-offset 0
//   ElG: 262144 u16 at float-offset 131072
//   e2 : 1024 floats at 262144
//   loss partials: 4096 floats at 263168
#define EH_OFF_F  0
#define EL_OFF_F  131072
#define E2_OFF_F  262144
#define PART_OFF_F 263168
#define NPART 4096

typedef __attribute__((ext_vector_type(8))) short bf16x8;
typedef __attribute__((ext_vector_type(4))) float f32x4;

static __device__ __forceinline__ unsigned short f2bf(float f) {
  unsigned int u = __float_as_uint(f);
  unsigned int r = (u + 0x7fffu + ((u >> 16) & 1u)) >> 16;
  return (unsigned short)r;
}
static __device__ __forceinline__ float bf2f(unsigned short h) {
  return __uint_as_float(((unsigned int)h) << 16);
}

// ---------------------------------------------------------------------------
// kA: blocks 0..255: x2[n] -> idx region (scratch). blocks 256..271: convert
// E -> (Eh,El) bf16 [c][k] + e2[c], wave per code (16 codes per wave).
// ---------------------------------------------------------------------------
__global__ __launch_bounds__(256) void kA_prep(const float* __restrict__ X,
                                               const float* __restrict__ E,
                                               float* __restrict__ out) {
  const int bid = blockIdx.x, tid = threadIdx.x;
  if (bid < 256) {
    const int n = bid * 256 + tid;
    float s = 0.0f;
#pragma unroll 8
    for (int d = 0; d < D_DIM; ++d) {
      float v = X[(size_t)d * N_TOK + n];
      s = fmaf(v, v, s);
    }
    out[IDX_OFF + n] = s;                    // x2 scratch
  } else {
    unsigned short* EhG = (unsigned short*)(out + EH_OFF_F);
    unsigned short* ElG = (unsigned short*)(out + EL_OFF_F);
    const int lane = tid & 63, w = tid >> 6;
#pragma unroll 1
    for (int cc = 0; cc < 16; ++cc) {
      const int c = (bid - 256) * 64 + w * 16 + cc;
      const float4 v = *(const float4*)(E + (size_t)c * D_DIM + lane * 4);
      unsigned short h0 = f2bf(v.x), h1 = f2bf(v.y), h2 = f2bf(v.z), h3 = f2bf(v.w);
      unsigned short l0 = f2bf(v.x - bf2f(h0)), l1 = f2bf(v.y - bf2f(h1));
      unsigned short l2 = f2bf(v.z - bf2f(h2)), l3 = f2bf(v.w - bf2f(h3));
      ushort4 hv = make_ushort4(h0, h1, h2, h3);
      ushort4 lv = make_ushort4(l0, l1, l2, l3);
      *(ushort4*)(EhG + (size_t)c * D_DIM + lane * 4) = hv;
      *(ushort4*)(ElG + (size_t)c * D_DIM + lane * 4) = lv;
      float s = v.x * v.x + v.y * v.y + v.z * v.z + v.w * v.w;
#pragma unroll
      for (int off = 32; off; off >>= 1) s += __shfl_down(s, off, 64);
      if (lane == 0) out[E2_OFF_F + c] = s;
    }
  }
}

// ---------------------------------------------------------------------------
// k2: distances via split-bf16 MFMA. Block = 64 tokens x 256 codes, 4 waves,
// wave w owns codes [w*64, w*64+64) as 4 n-tiles of 16. K chunk = 32.
// Pipelined (T14): per chunk, issue B (Eh/El) global loads FIRST so their L2
// latency hides under convert+ds_write+barrier; prefetch the NEXT X chunk
// into registers before the barrier so its HBM/L3 latency hides under the
// A-reads + 48 MFMAs. LDS X tile double-buffered -> ONE barrier per chunk.
// vmcnt queue order [X_k, B_k, X_{k+1}] keeps waits counted (never drains
// the prefetch). 1D grid 4096 with XCD-swizzle: all 4 code-tiles (bx) of a
// token-tile (by) land on the SAME XCD (bids congruent mod 8) so the X slice
// is an L2 hit for 3 of 4 readers instead of 4x HBM/L3 traffic.
// Numerics identical to the unpipelined version (same rounding, same MFMA
// accumulation order).
// ---------------------------------------------------------------------------
#define TM 64
#define TC 256
#define BK 32
#define XS 40   // u16 stride per token row (32 + 8 pad), 80B: 16B-aligned

__global__ __launch_bounds__(256) void k2_dist(const float* __restrict__ X,
                                               float* __restrict__ out) {
  __shared__ __align__(16) unsigned short xh[2][TM * XS];
  __shared__ __align__(16) unsigned short xl[2][TM * XS];

  const unsigned short* __restrict__ EhG = (const unsigned short*)(out + EH_OFF_F);
  const unsigned short* __restrict__ ElG = (const unsigned short*)(out + EL_OFF_F);

  const int tid = threadIdx.x;
  const int lane = tid & 63, wave = tid >> 6;

  // XCD-swizzled decode: bid = slot*8 + xcd; slot = s2*4 + bx; by = xcd*128+s2.
  // The 4 blocks sharing token-tile `by` have bids {32*s2+xcd+8*bx} == xcd mod 8.
  const int bid = blockIdx.x;
  const int xcd = bid & 7;
  const int slot = bid >> 3;
  const int bx = slot & 3;
  const int by = xcd * 128 + (slot >> 2);
  const int c0 = bx * TC;
  const int n0 = by * TM;

  const int wc = c0 + wave * 64;             // this wave's 64 codes
  const int m = lane & 15;                   // row/col within 16-tile
  const int q = lane >> 4;                   // k-quad

  f32x4 acc[4][4];                           // [m-tile][n-tile]
#pragma unroll
  for (int i = 0; i < 4; ++i)
#pragma unroll
    for (int t = 0; t < 4; ++t) acc[i][t] = (f32x4){0.f, 0.f, 0.f, 0.f};

  const int sn = lane;                       // staged token (0..63)
  const int kg = wave;                       // staged k-group (0..3) -> 8 k's

  // prologue: X chunk 0 -> regs (only this load's latency is ever exposed)
  float xv[8];
  {
    const float* xp = X + (size_t)(kg * 8) * N_TOK + n0 + sn;
#pragma unroll
    for (int j = 0; j < 8; ++j) xv[j] = xp[(size_t)j * N_TOK];
  }

#pragma unroll 1
  for (int kb = 0; kb < D_DIM; kb += BK) {
    const int p = (kb >> 5) & 1;

    // ---- B fragments for THIS chunk: issue first, consume after barrier ----
    bf16x8 bh[4], bl[4];
#pragma unroll
    for (int t = 0; t < 4; ++t) {
      const size_t eoff = (size_t)(wc + t * 16 + m) * D_DIM + kb + q * 8;
      bh[t] = *(const bf16x8*)(EhG + eoff);
      bl[t] = *(const bf16x8*)(ElG + eoff);
    }

    // ---- convert current X regs -> bf16 hi/lo, stage to LDS buf p ----
    unsigned short hh[8], ll[8];
#pragma unroll
    for (int j = 0; j < 8; ++j) {
      hh[j] = f2bf(xv[j]);
      ll[j] = f2bf(xv[j] - bf2f(hh[j]));
    }
    *(bf16x8*)&xh[p][sn * XS + kg * 8] = *(bf16x8*)hh;
    *(bf16x8*)&xl[p][sn * XS + kg * 8] = *(bf16x8*)ll;

    // ---- prefetch NEXT X chunk into regs (in flight across the barrier) ----
    if (kb + BK < D_DIM) {
      const float* xp = X + (size_t)(kb + BK + kg * 8) * N_TOK + n0 + sn;
#pragma unroll
      for (int j = 0; j < 8; ++j) xv[j] = xp[(size_t)j * N_TOK];
    }

    __syncthreads();

    // ---- A fragments from LDS buf p ----
    bf16x8 ah[4], al[4];
#pragma unroll
    for (int i = 0; i < 4; ++i) {
      const int ro = (i * 16 + m) * XS + q * 8;
      ah[i] = *(const bf16x8*)&xh[p][ro];
      al[i] = *(const bf16x8*)&xl[p][ro];
    }
    // ---- 48 MFMAs: hi*hi + hi*lo + lo*hi ----
#pragma unroll
    for (int i = 0; i < 4; ++i)
#pragma unroll
      for (int t = 0; t < 4; ++t) {
        acc[i][t] = __builtin_amdgcn_mfma_f32_16x16x32_bf16(ah[i], bh[t], acc[i][t], 0, 0, 0);
        acc[i][t] = __builtin_amdgcn_mfma_f32_16x16x32_bf16(ah[i], bl[t], acc[i][t], 0, 0, 0);
        acc[i][t] = __builtin_amdgcn_mfma_f32_16x16x32_bf16(al[i], bh[t], acc[i][t], 0, 0, 0);
      }
    // no trailing barrier: double-buffered LDS, WAR safe (reads drain at the
    // next iteration's barrier before anyone can write this buffer again)
  }

  // ---- epilogue: d2 = x2 + e2 - 2*xe; dist = -sqrt(max(d2,0)) ----
  float e2v[4];
#pragma unroll
  for (int t = 0; t < 4; ++t) e2v[t] = out[E2_OFF_F + wc + t * 16 + m];

#pragma unroll
  for (int i = 0; i < 4; ++i) {
#pragma unroll
    for (int r = 0; r < 4; ++r) {
      const int tok = n0 + i * 16 + q * 4 + r;
      const float x2v = out[IDX_OFF + tok];
      const size_t row = DIST_OFF + (size_t)tok * C_NUM;
#pragma unroll
      for (int t = 0; t < 4; ++t) {
        float d2 = fmaf(-2.0f, acc[i][t][r], x2v + e2v[t]);
        d2 = fmaxf(d2, 0.0f);
        out[row + wc + t * 16 + m] = -sqrtf(d2);
      }
    }
  }
}

// ---------------------------------------------------------------------------
// k3: wave per token (4 tokens per wave, 4 waves per block -> 16 tokens/blk).
// Approx argmax from stored distances; candidates within MARGIN of best get
// exact fp32 d2 (wave-cooperative), lexicographic (d2, idx) winner -> matches
// reference argmax incl. first-index tie-break. Per-block loss partial.
// ---------------------------------------------------------------------------
#define MARGIN 0.01f

__global__ __launch_bounds__(256) void k3_argmax(const float* __restrict__ X,
                                                 const float* __restrict__ E,
                                                 float* __restrict__ out) {
  __shared__ float lsum[4];
  const int tid = threadIdx.x, lane = tid & 63, w = tid >> 6;
  float wloss = 0.0f;

#pragma unroll 1
  for (int it = 0; it < 4; ++it) {
    const int n = blockIdx.x * 16 + w * 4 + it;
    const float* row = out + DIST_OFF + (size_t)n * C_NUM;

    float v[16];
    float best = -3.4e38f;
    int bi = 0x7fffffff;
#pragma unroll
    for (int j = 0; j < 16; ++j) {
      v[j] = row[j * 64 + lane];
      if (v[j] > best) { best = v[j]; bi = j * 64 + lane; }
    }
#pragma unroll
    for (int off = 32; off; off >>= 1) {
      const float ov = __shfl_xor(best, off, 64);
      const int oi = __shfl_xor(bi, off, 64);
      if (ov > best || (ov == best && oi < bi)) { best = ov; bi = oi; }
    }
    // candidate set within margin
    const float thr = best - MARGIN;
    unsigned long long masks[16];
    int total = 0;
#pragma unroll
    for (int j = 0; j < 16; ++j) {
      masks[j] = __ballot(v[j] > thr);
      total += __popcll(masks[j]);
    }
    float best_d2 = best * best;
    int best_idx = bi;
    if (total > 1) {
      best_d2 = 3.4e38f;
      best_idx = 0x7fffffff;
      for (int j = 0; j < 16; ++j) {
        unsigned long long mm = masks[j];
        while (mm) {
          const int l = __ffsll((long long)mm) - 1;
          mm &= mm - 1;
          const int c = j * 64 + l;
          // exact fp32 d2, wave-cooperative over d
          float sx = 0.f, se = 0.f, sxe = 0.f;
#pragma unroll
          for (int r = 0; r < 4; ++r) {
            const int d = r * 64 + lane;
            const float xv = X[(size_t)d * N_TOK + n];
            const float ev = E[(size_t)c * D_DIM + d];
            sx = fmaf(xv, xv, sx);
            se = fmaf(ev, ev, se);
            sxe = fmaf(xv, ev, sxe);
          }
          float d2 = fmaf(-2.f, sxe, sx + se);
#pragma unroll
          for (int off = 32; off; off >>= 1) d2 += __shfl_xor(d2, off, 64);
          d2 = fmaxf(d2, 0.f);
          if (d2 < best_d2 || (d2 == best_d2 && c < best_idx)) {
            best_d2 = d2; best_idx = c;
          }
        }
      }
    }
    if (lane == 0) out[IDX_OFF + n] = (float)best_idx;
    wloss += best_d2;
  }
  if (lane == 0) lsum[w] = wloss;
  __syncthreads();
  if (tid == 0)
    out[PART_OFF_F + blockIdx.x] = lsum[0] + lsum[1] + lsum[2] + lsum[3];
}

// ---------------------------------------------------------------------------
// k3b: reduce 4096 partials -> loss (single block; no contended atomics).
// ---------------------------------------------------------------------------
__global__ __launch_bounds__(256) void k3b_loss(float* __restrict__ out) {
  __shared__ float red[4];
  const int tid = threadIdx.x, lane = tid & 63, w = tid >> 6;
  float s = 0.0f;
#pragma unroll
  for (int i = 0; i < NPART / 256; ++i) s += out[PART_OFF_F + i * 256 + tid];
#pragma unroll
  for (int off = 32; off; off >>= 1) s += __shfl_down(s, off, 64);
  if (lane == 0) red[w] = s;
  __syncthreads();
  if (tid == 0)
    out[LOSS_OFF] = (red[0] + red[1] + red[2] + red[3]) *
                    (0.25f / ((float)N_TOK * (float)D_DIM));
}

// ---------------------------------------------------------------------------
// k4: out[d][n] = E[idx[n]][d]. Thread owns 4 consecutive n, float4 writes.
// grid (64, 8): y-splits d for occupancy. Overwrites the scratch region last.
// ---------------------------------------------------------------------------
__global__ __launch_bounds__(256) void k4_gather(const float* __restrict__ E,
                                                 float* __restrict__ out) {
  const int g = blockIdx.x * 256 + threadIdx.x;   // n-group
  const int n = g * 4;
  const int i0 = (int)out[IDX_OFF + n + 0];
  const int i1 = (int)out[IDX_OFF + n + 1];
  const int i2 = (int)out[IDX_OFF + n + 2];
  const int i3 = (int)out[IDX_OFF + n + 3];
  const float* e0 = E + (size_t)i0 * D_DIM;
  const float* e1 = E + (size_t)i1 * D_DIM;
  const float* e2 = E + (size_t)i2 * D_DIM;
  const float* e3 = E + (size_t)i3 * D_DIM;
  const int d0 = blockIdx.y * 32;
#pragma unroll 4
  for (int d = d0; d < d0 + 32; ++d) {
    float4 wv = make_float4(e0[d], e1[d], e2[d], e3[d]);
    *(float4*)&out[(size_t)d * N_TOK + n] = wv;
  }
}

extern "C" void kernel_launch(void* const* d_in, const int* in_sizes, int n_in,
                              void* d_out, int out_size, void* d_ws, size_t ws_size,
                              hipStream_t stream) {
  const float* X = (const float*)d_in[0];   // (1, 256, 65536)
  const float* E = (const float*)d_in[1];   // (1, 1024, 256)
  float* out = (float*)d_out;

  hipLaunchKernelGGL(kA_prep, dim3(272), dim3(256), 0, stream, X, E, out);
  hipLaunchKernelGGL(k2_dist, dim3((C_NUM / TC) * (N_TOK / TM)), dim3(256), 0,
                     stream, X, out);
  hipLaunchKernelGGL(k3_argmax, dim3(N_TOK / 16), dim3(256), 0, stream, X, E, out);
  hipLaunchKernelGGL(k3b_loss, dim3(1), dim3(256), 0, stream, out);
  hipLaunchKernelGGL(k4_gather, dim3(N_TOK / 4 / 256, 8), dim3(256), 0, stream,
                     E, out);
}